// Round 3
// baseline (241.823 us; speedup 1.0000x reference)
//
#include <hip/hip_runtime.h>
#include <hip/hip_bf16.h>
#include <stdint.h>

#define LN_EPS 1e-5f

typedef __attribute__((ext_vector_type(4))) float f32x4;
typedef __attribute__((ext_vector_type(8))) short bf16x8;

#define D_ 1024
#define P_ 512
#define N_ 32768   // B*S rows

__device__ __forceinline__ short f2bf(float x) {
  union { __hip_bfloat16 h; short s; } u; u.h = __float2bfloat16(x); return u.s;
}

// ---------------- kernel: scatter W rows into W2f ----------------
// W2f[c,p] = sum_{d: s5[d]==c} W[d,p];  b2[c] = sum_{d: s5[d]==c} b[d]
__global__ void k_scatter(const float* __restrict__ W, const float* __restrict__ bias,
                          const int* __restrict__ s5,
                          float* __restrict__ w2f, float* __restrict__ b2) {
  int d = blockIdx.x;                  // 0..1023
  int c = s5[d];
  const float* wrow = W + (size_t)d * P_;
  float* dst = w2f + (size_t)c * P_;
  for (int p = threadIdx.x; p < P_; p += 256)
    atomicAdd(&dst[p], wrow[p]);
  if (threadIdx.x == 0) atomicAdd(&b2[c], bias[d]);
}

// ---------------- kernel: W2f -> bf16 ----------------
__global__ void k_conv(const float* __restrict__ w2f, __hip_bfloat16* __restrict__ w2b) {
  int i = blockIdx.x * 256 + threadIdx.x;
  if (i < D_ * P_) w2b[i] = __float2bfloat16(w2f[i]);
}

// ---------------- kernel: pre-gather LN affine params ----------------
__global__ void k_prep(const float* __restrict__ lnw, const float* __restrict__ lnb,
                       const int* __restrict__ s3,
                       float* __restrict__ lnwg, float* __restrict__ lnbg) {
  int p = threadIdx.x;                 // 512 threads, 1 block
  int i = s3[p];
  lnwg[p] = lnw[i];
  lnbg[p] = lnb[i];
}

// ---------------- fused: LN + gather (to LDS) + MFMA GEMM + residual ----------------
// One block per 128 rows; g[128][512] bf16 lives entirely in LDS (128 KB).
// GEMM main loop has NO barriers: A-frags from swizzled LDS, B-frags direct
// from global (W2b is 1 MB -> L2-resident), acc in VGPRs.
#define BM 128
#define THREADS 512

__global__ __launch_bounds__(THREADS, 2) void k_fused(
    const float* __restrict__ hid,     // [N_,D_] fp32
    const float* __restrict__ lnwg,    // [P_]
    const float* __restrict__ lnbg,    // [P_]
    const int*   __restrict__ s3,      // [P_]
    const __hip_bfloat16* __restrict__ w2b,  // [D_,P_] bf16
    const float* __restrict__ b2,      // [D_]
    float* __restrict__ out) {         // [N_,D_] fp32
  __shared__ __align__(16) char g_lds[BM * P_ * 2];   // 128 KB

  const int bm   = blockIdx.x * BM;
  const int t    = threadIdx.x;
  const int lane = t & 63;
  const int wid  = t >> 6;            // 8 waves

  // ===== Phase 1: LayerNorm + gather =====
  {
    // per-lane gather metadata: p = lane*8 .. lane*8+7
    const int4   i0 = ((const int4*)s3)[lane * 2];
    const int4   i1 = ((const int4*)s3)[lane * 2 + 1];
    const float4 w0 = ((const float4*)lnwg)[lane * 2];
    const float4 w1 = ((const float4*)lnwg)[lane * 2 + 1];
    const float4 a0 = ((const float4*)lnbg)[lane * 2];
    const float4 a1 = ((const float4*)lnbg)[lane * 2 + 1];

    for (int rr = 0; rr < 16; ++rr) {
      const int r = rr * 8 + wid;                  // row within tile, one wave per row
      const float* xr = hid + (size_t)(bm + r) * D_;
      const float4 v0 = ((const float4*)xr)[lane];
      const float4 v1 = ((const float4*)xr)[64 + lane];
      const float4 v2 = ((const float4*)xr)[128 + lane];
      const float4 v3 = ((const float4*)xr)[192 + lane];
      float s  = (v0.x + v0.y + v0.z + v0.w) + (v1.x + v1.y + v1.z + v1.w)
               + (v2.x + v2.y + v2.z + v2.w) + (v3.x + v3.y + v3.z + v3.w);
      float s2 = (v0.x*v0.x + v0.y*v0.y + v0.z*v0.z + v0.w*v0.w)
               + (v1.x*v1.x + v1.y*v1.y + v1.z*v1.z + v1.w*v1.w)
               + (v2.x*v2.x + v2.y*v2.y + v2.z*v2.z + v2.w*v2.w)
               + (v3.x*v3.x + v3.y*v3.y + v3.z*v3.z + v3.w*v3.w);
      #pragma unroll
      for (int off = 32; off > 0; off >>= 1) {
        s  += __shfl_down(s, off);
        s2 += __shfl_down(s2, off);
      }
      s  = __shfl(s, 0);
      s2 = __shfl(s2, 0);
      const float mu  = s * (1.f / D_);
      const float inv = rsqrtf(s2 * (1.f / D_) - mu * mu + LN_EPS);

      // gather 8 channels from the just-read row (L1-hit scalar loads)
      bf16x8 gv;
      gv[0] = f2bf((xr[i0.x] - mu) * inv * w0.x + a0.x);
      gv[1] = f2bf((xr[i0.y] - mu) * inv * w0.y + a0.y);
      gv[2] = f2bf((xr[i0.z] - mu) * inv * w0.z + a0.z);
      gv[3] = f2bf((xr[i0.w] - mu) * inv * w0.w + a0.w);
      gv[4] = f2bf((xr[i1.x] - mu) * inv * w1.x + a1.x);
      gv[5] = f2bf((xr[i1.y] - mu) * inv * w1.y + a1.y);
      gv[6] = f2bf((xr[i1.z] - mu) * inv * w1.z + a1.z);
      gv[7] = f2bf((xr[i1.w] - mu) * inv * w1.w + a1.w);
      // swizzled write: byte ^= ((row&7)<<4); lanes hit 64 distinct 16B slots
      const int byteoff = (r * 1024 + lane * 16) ^ ((r & 7) << 4);
      *(bf16x8*)(g_lds + byteoff) = gv;
    }
  }
  __syncthreads();   // the only barrier

  // ===== Phase 2: GEMM  out[128][1024] = g x W2^T + hid + b2 =====
  const int wr = wid >> 2;            // 2 wave-rows x 4 wave-cols, 64x64 tile each
  const int wc = wid & 3;

  for (int nc = 0; nc < 4; ++nc) {    // 4 chunks of 256 output cols
    f32x4 acc[4][4] = {};
    #pragma unroll
    for (int ks = 0; ks < 8; ++ks) {  // K = 512, BK = 64
      bf16x8 af[2][4], bfr[2][4];
      #pragma unroll
      for (int kk = 0; kk < 2; ++kk) {
        const int kb = ks * 128 + kk * 64 + ((lane >> 4) << 4);   // byte offset in g row
        #pragma unroll
        for (int mi = 0; mi < 4; ++mi) {
          const int r = wr * 64 + mi * 16 + (lane & 15);
          af[kk][mi] = *(const bf16x8*)(g_lds + ((r * 1024 + kb) ^ ((r & 7) << 4)));
        }
        const int ke = ks * 64 + kk * 32 + ((lane >> 4) << 3);    // elem offset in w2b row
        #pragma unroll
        for (int ni = 0; ni < 4; ++ni) {
          const int c = nc * 256 + wc * 64 + ni * 16 + (lane & 15);
          bfr[kk][ni] = *(const bf16x8*)(w2b + (size_t)c * P_ + ke);
        }
      }
      #pragma unroll
      for (int kk = 0; kk < 2; ++kk)
        #pragma unroll
        for (int mi = 0; mi < 4; ++mi)
          #pragma unroll
          for (int ni = 0; ni < 4; ++ni)
            acc[mi][ni] = __builtin_amdgcn_mfma_f32_16x16x32_bf16(
                af[kk][mi], bfr[kk][ni], acc[mi][ni], 0, 0, 0);
    }
    // epilogue: C/D layout col=lane&15 (N), row=(lane>>4)*4+reg (M)
    const int row0 = bm + wr * 64 + ((lane >> 4) << 2);
    const int col0 = nc * 256 + wc * 64 + (lane & 15);
    #pragma unroll
    for (int ni = 0; ni < 4; ++ni) {
      const int col = col0 + ni * 16;
      const float bias = b2[col];
      #pragma unroll
      for (int mi = 0; mi < 4; ++mi) {
        const int rw = row0 + mi * 16;
        #pragma unroll
        for (int r4 = 0; r4 < 4; ++r4) {
          const size_t idx = (size_t)(rw + r4) * D_ + col;
          out[idx] = hid[idx] + acc[mi][ni][r4] + bias;
        }
      }
    }
  }
}

extern "C" void kernel_launch(void* const* d_in, const int* in_sizes, int n_in,
                              void* d_out, int out_size, void* d_ws, size_t ws_size,
                              hipStream_t stream) {
  const float* hid  = (const float*)d_in[0];
  const float* lnw  = (const float*)d_in[1];
  const float* lnb  = (const float*)d_in[2];
  const float* W    = (const float*)d_in[3];
  const float* bias = (const float*)d_in[4];
  const int*   s3   = (const int*)d_in[5];
  const int*   s5   = (const int*)d_in[6];
  float* out = (float*)d_out;

  // workspace layout:
  //   [0, 2MB)            W2f  fp32 [1024][512]
  //   [2MB, +4KB)         b2   fp32 [1024]
  //   [2MB+4KB, +1MB)     W2b  bf16 [1024][512]
  //   [3MB+4KB, +2KB)     lnwg fp32 [512]
  //   [3MB+6KB, +2KB)     lnbg fp32 [512]
  char* ws = (char*)d_ws;
  float*          w2f  = (float*)ws;
  float*          b2   = (float*)(ws + 2097152);
  __hip_bfloat16* w2b  = (__hip_bfloat16*)(ws + 2101248);
  float*          lnwg = (float*)(ws + 3149824);
  float*          lnbg = (float*)(ws + 3151872);

  hipMemsetAsync(ws, 0, 2101248, stream);   // zero W2f + b2
  k_scatter<<<dim3(1024), dim3(256), 0, stream>>>(W, bias, s5, w2f, b2);
  k_conv   <<<dim3(2048), dim3(256), 0, stream>>>(w2f, w2b);
  k_prep   <<<dim3(1),    dim3(512), 0, stream>>>(lnw, lnb, s3, lnwg, lnbg);
  k_fused  <<<dim3(N_/BM), dim3(THREADS), 0, stream>>>(hid, lnwg, lnbg, s3, w2b, b2, out);
}